// Round 1
// baseline (894.114 us; speedup 1.0000x reference)
//
#include <hip/hip_runtime.h>
#include <cstdint>
#include <cstddef>

#define D 128

// ---------------- utility kernels ----------------
__global__ void zero_i32_kernel(int* p, int n) {
  int i = blockIdx.x * blockDim.x + threadIdx.x;
  if (i < n) p[i] = 0;
}
__global__ void zero_f32_kernel(float* p, int n) {
  int i = blockIdx.x * blockDim.x + threadIdx.x;
  if (i < n) p[i] = 0.f;
}

// ---------------- CSR build ----------------
__global__ void count_kernel(const int* __restrict__ dst0, const int* __restrict__ dst1,
                             int* cnt0, int* cnt1, int E) {
  int e = blockIdx.x * blockDim.x + threadIdx.x;
  if (e < E) {
    atomicAdd(&cnt0[dst0[e]], 1);
    atomicAdd(&cnt1[dst1[e]], 1);
  }
}

__global__ __launch_bounds__(1024) void scan_kernel(const int* cnt0, int* off0,
                                                    const int* cnt1, int* off1, int n) {
  const int* cnt = (blockIdx.x == 0) ? cnt0 : cnt1;
  int* off = (blockIdx.x == 0) ? off0 : off1;
  __shared__ int tsum[1024];
  int tid = threadIdx.x;
  int per = (n + 1023) >> 10;
  int start = tid * per;
  int end = start + per; if (end > n) end = n;
  int s = 0;
  for (int i = start; i < end; i++) s += cnt[i];
  tsum[tid] = s;
  __syncthreads();
  for (int d = 1; d < 1024; d <<= 1) {
    int v = (tid >= d) ? tsum[tid - d] : 0;
    __syncthreads();
    if (tid >= d) tsum[tid] += v;
    __syncthreads();
  }
  int run = (tid > 0) ? tsum[tid - 1] : 0;
  for (int i = start; i < end; i++) { off[i] = run; run += cnt[i]; }
  if (tid == 1023) off[n] = run;
}

__global__ void dinv_kernel(int* cnt0, int* cnt1, float* dinv0, float* dinv1, int n) {
  int i = blockIdx.x * blockDim.x + threadIdx.x;
  if (i < n) {
    dinv0[i] = rsqrtf((float)cnt0[i] + 1.0f);
    dinv1[i] = rsqrtf((float)cnt1[i] + 1.0f);
    cnt0[i] = 0;  // reuse as fill cursor
    cnt1[i] = 0;
  }
}

__global__ void fill_kernel(const int* __restrict__ src0, const int* __restrict__ dst0,
                            const int* __restrict__ src1, const int* __restrict__ dst1,
                            const int* __restrict__ off0, const int* __restrict__ off1,
                            int* cnt0, int* cnt1, int* csr0, int* csr1, int E) {
  int e = blockIdx.x * blockDim.x + threadIdx.x;
  if (e < E) {
    int d = dst0[e];
    int p = atomicAdd(&cnt0[d], 1);
    csr0[off0[d] + p] = src0[e];
    d = dst1[e];
    p = atomicAdd(&cnt1[d], 1);
    csr1[off1[d] + p] = src1[e];
  }
}

// ---------------- aggregation (gather, warp per node) ----------------
__global__ __launch_bounds__(256) void gather_kernel(
    const float* __restrict__ hW0, const float* __restrict__ hW1,
    const float* __restrict__ dinv0, const float* __restrict__ dinv1,
    const int* __restrict__ off0, const int* __restrict__ csr0,
    const int* __restrict__ off1, const int* __restrict__ csr1,
    const float* __restrict__ b0, const float* __restrict__ b1,
    float* __restrict__ outh, int n) {
  int warp = threadIdx.x >> 6;
  int lane = threadIdx.x & 63;
  int node = blockIdx.x * 4 + warp;
  if (node >= n) return;
  const float2* h0 = (const float2*)hW0;
  const float2* h1 = (const float2*)hW1;
  float2 s0 = make_float2(0.f, 0.f), s1 = make_float2(0.f, 0.f);
  int a = off0[node], b = off0[node + 1];
  for (int j = a; j < b; j++) {
    int s = csr0[j];
    float w = dinv0[s];
    float2 v = h0[(size_t)s * 64 + lane];
    s0.x += w * v.x; s0.y += w * v.y;
  }
  a = off1[node]; b = off1[node + 1];
  for (int j = a; j < b; j++) {
    int s = csr1[j];
    float w = dinv1[s];
    float2 v = h1[(size_t)s * 64 + lane];
    s1.x += w * v.x; s1.y += w * v.y;
  }
  float d0 = dinv0[node], d1 = dinv1[node];
  float2 v0 = h0[(size_t)node * 64 + lane];
  float2 v1 = h1[(size_t)node * 64 + lane];
  int c = lane * 2;
  float2 r;
  r.x = d0 * s0.x + d1 * s1.x + d0 * d0 * v0.x + d1 * d1 * v1.x + b0[c] + b1[c];
  r.y = d0 * s0.y + d1 * s1.y + d0 * d0 * v0.y + d1 * d1 * v1.y + b0[c + 1] + b1[c + 1];
  ((float2*)outh)[(size_t)node * 64 + lane] = r;
}

// ---------------- BatchNorm ----------------
__global__ __launch_bounds__(256) void stats_kernel(const float* __restrict__ h,
                                                    float* colsum, float* colsumsq,
                                                    int n, int rpb) {
  int col = threadIdx.x & 127;
  int sub = threadIdx.x >> 7;
  int r0 = blockIdx.x * rpb;
  int r1 = r0 + rpb; if (r1 > n) r1 = n;
  float s = 0.f, ss = 0.f;
  for (int r = r0 + sub; r < r1; r += 2) {
    float v = h[(size_t)r * D + col];
    s += v; ss += v * v;
  }
  __shared__ float ls[256], lss[256];
  ls[threadIdx.x] = s; lss[threadIdx.x] = ss;
  __syncthreads();
  if (sub == 0) {
    s += ls[threadIdx.x + 128];
    ss += lss[threadIdx.x + 128];
    atomicAdd(&colsum[col], s);
    atomicAdd(&colsumsq[col], ss);
  }
}

__global__ void bn_coef_kernel(const float* colsum, const float* colsumsq,
                               const float* __restrict__ g, const float* __restrict__ bt,
                               float* colscale, float* colshift, int n) {
  int c = threadIdx.x;
  if (c < D) {
    float invn = 1.0f / (float)n;
    float mu = colsum[c] * invn;
    float var = colsumsq[c] * invn - mu * mu;
    float sc = g[c] * rsqrtf(var + 1e-5f);
    colscale[c] = sc;
    colshift[c] = bt[c] - mu * sc;
  }
}

__global__ void bn_apply_kernel(float* __restrict__ h,
                                const float* __restrict__ colscale,
                                const float* __restrict__ colshift,
                                int n, int relu) {
  int idx = blockIdx.x * blockDim.x + threadIdx.x;
  int total = n * 32;
  if (idx >= total) return;
  int r = idx >> 5;
  int c4 = (idx & 31) * 4;
  float4 v = *(float4*)(h + (size_t)r * D + c4);
  float4 sc = *(const float4*)(colscale + c4);
  float4 sh = *(const float4*)(colshift + c4);
  v.x = v.x * sc.x + sh.x;
  v.y = v.y * sc.y + sh.y;
  v.z = v.z * sc.z + sh.z;
  v.w = v.w * sc.w + sh.w;
  if (relu) {
    v.x = fmaxf(v.x, 0.f); v.y = fmaxf(v.y, 0.f);
    v.z = fmaxf(v.z, 0.f); v.w = fmaxf(v.w, 0.f);
  }
  *(float4*)(h + (size_t)r * D + c4) = v;
}

// ---------------- fp32 matmul  C[n,128] = A[n,128] @ W[128,128] (+bias) + epilogue
// EPI: 0=none, 1=relu, 2=tanh, 3=tanh+l2norm(row), 4=l2norm(row)
template <int EPI>
__global__ __launch_bounds__(256) void mm_kernel(const float* __restrict__ A,
                                                 const float* __restrict__ W,
                                                 const float* __restrict__ bias,
                                                 float* __restrict__ C, int n) {
  __shared__ float As[64][68];
  __shared__ float Ws[64][128];
  const int t = threadIdx.x;
  const int rg = t >> 5;   // 0..7  (8 rows each)
  const int cg = t & 31;   // 0..31 (4 cols each)
  const int row0 = blockIdx.x * 64;

  float acc[8][4];
  float bv[4] = {0.f, 0.f, 0.f, 0.f};
  if (bias) {
    float4 b4 = *(const float4*)(bias + cg * 4);
    bv[0] = b4.x; bv[1] = b4.y; bv[2] = b4.z; bv[3] = b4.w;
  }
#pragma unroll
  for (int i = 0; i < 8; i++)
#pragma unroll
    for (int j = 0; j < 4; j++) acc[i][j] = bv[j];

  for (int kc = 0; kc < 2; kc++) {
    const int kk = kc * 64;
    // stage A tile: 64 rows x 64 ks
#pragma unroll
    for (int i = 0; i < 4; i++) {
      int idx = t + i * 256;       // 0..1023
      int r = idx >> 4;            // 16 float4 per row
      int c4 = idx & 15;
      int ar = row0 + r;
      ar = (ar < n) ? ar : (n - 1);
      float4 v = *(const float4*)(A + (size_t)ar * 128 + kk + c4 * 4);
      *(float4*)(&As[r][c4 * 4]) = v;
    }
    // stage W tile: 64 ks x 128 cols
#pragma unroll
    for (int i = 0; i < 8; i++) {
      int idx = t + i * 256;       // 0..2047
      int wk = idx >> 5;
      int wc = idx & 31;
      *(float4*)(&Ws[wk][wc * 4]) = *(const float4*)(W + (size_t)(kk + wk) * 128 + wc * 4);
    }
    __syncthreads();
#pragma unroll
    for (int k4 = 0; k4 < 16; k4++) {
      float a4[8][4];
      float w4[4][4];
#pragma unroll
      for (int i = 0; i < 8; i++) *(float4*)a4[i] = *(const float4*)(&As[rg * 8 + i][k4 * 4]);
#pragma unroll
      for (int j = 0; j < 4; j++) *(float4*)w4[j] = *(const float4*)(&Ws[k4 * 4 + j][cg * 4]);
#pragma unroll
      for (int i = 0; i < 8; i++)
#pragma unroll
        for (int k2 = 0; k2 < 4; k2++)
#pragma unroll
          for (int j = 0; j < 4; j++) acc[i][j] += a4[i][k2] * w4[k2][j];
    }
    __syncthreads();
  }

  // epilogue
  if (EPI == 1) {
#pragma unroll
    for (int i = 0; i < 8; i++)
#pragma unroll
      for (int j = 0; j < 4; j++) acc[i][j] = fmaxf(acc[i][j], 0.f);
  }
  if (EPI == 2 || EPI == 3) {
#pragma unroll
    for (int i = 0; i < 8; i++)
#pragma unroll
      for (int j = 0; j < 4; j++) acc[i][j] = tanhf(acc[i][j]);
  }
  if (EPI == 3 || EPI == 4) {
#pragma unroll
    for (int i = 0; i < 8; i++) {
      float rs = acc[i][0] * acc[i][0] + acc[i][1] * acc[i][1] +
                 acc[i][2] * acc[i][2] + acc[i][3] * acc[i][3];
      rs += __shfl_xor(rs, 1);
      rs += __shfl_xor(rs, 2);
      rs += __shfl_xor(rs, 4);
      rs += __shfl_xor(rs, 8);
      rs += __shfl_xor(rs, 16);
      float scl = 1.f / fmaxf(sqrtf(rs), 1e-12f);
#pragma unroll
      for (int j = 0; j < 4; j++) acc[i][j] *= scl;
    }
  }
#pragma unroll
  for (int i = 0; i < 8; i++) {
    int r = row0 + rg * 8 + i;
    if (r < n) {
      *(float4*)(C + (size_t)r * 128 + cg * 4) =
          make_float4(acc[i][0], acc[i][1], acc[i][2], acc[i][3]);
    }
  }
}

// ---------------- launch ----------------
extern "C" void kernel_launch(void* const* d_in, const int* in_sizes, int n_in,
                              void* d_out, int out_size, void* d_ws, size_t ws_size,
                              hipStream_t stream) {
  const float* x      = (const float*)d_in[0];
  const int*   ei0    = (const int*)d_in[1];
  const int*   ei1    = (const int*)d_in[2];
  const float* W0     = (const float*)d_in[3];
  const float* b0     = (const float*)d_in[4];
  const float* W1     = (const float*)d_in[5];
  const float* b1     = (const float*)d_in[6];
  const float* gamma  = (const float*)d_in[7];
  const float* beta   = (const float*)d_in[8];
  const float* emb1_W = (const float*)d_in[9];
  const float* emb1_b = (const float*)d_in[10];
  const float* emb2_W = (const float*)d_in[11];
  const float* emb2_b = (const float*)d_in[12];
  const float* ph1_Wa = (const float*)d_in[13];
  const float* ph1_ba = (const float*)d_in[14];
  const float* ph1_Wb = (const float*)d_in[15];
  const float* ph1_bb = (const float*)d_in[16];
  const float* ph2_Wa = (const float*)d_in[17];
  const float* ph2_ba = (const float*)d_in[18];
  const float* ph2_Wb = (const float*)d_in[19];
  const float* ph2_bb = (const float*)d_in[20];

  const int N = in_sizes[0] / D;
  const int E = in_sizes[1] / 2;
  const size_t ND = (size_t)N * D;
  float* out = (float*)d_out;

  // workspace carve (256B aligned)
  char* p = (char*)d_ws;
  char* pend = p + ws_size;
  auto carve = [&](size_t bytes) -> void* {
    void* r = (void*)p;
    p += (bytes + 255) & ~(size_t)255;
    return r;
  };
  int*   cnt0  = (int*)carve((size_t)2 * N * 4);   // cnt0 and cnt1 contiguous
  int*   cnt1  = cnt0 + N;
  int*   off0  = (int*)carve((size_t)(N + 1) * 4);
  int*   off1  = (int*)carve((size_t)(N + 1) * 4);
  float* dinv0 = (float*)carve((size_t)N * 4);
  float* dinv1 = (float*)carve((size_t)N * 4);
  int*   csr0  = (int*)carve((size_t)E * 4);
  int*   csr1  = (int*)carve((size_t)E * 4);
  float* stats = (float*)carve(512 * 4);  // sum[128] sumsq[128] scale[128] shift[128]
  float* hW1   = (float*)carve(ND * 4);

  float *hbuf, *hW0;
  if ((size_t)(pend - p) >= 2 * ND * 4 + 512) {
    hbuf = (float*)carve(ND * 4);
    hW0  = (float*)carve(ND * 4);
  } else {
    // fallback: use p1/p2 output slots as scratch (fully rewritten at the end)
    hbuf = out + 2 * ND;
    hW0  = out + 3 * ND;
  }

  const int TPB = 256;
  const int gridE = (E + TPB - 1) / TPB;
  const int MMG = (N + 63) / 64;

  // --- build degree + CSR (static across layers) ---
  zero_i32_kernel<<<(2 * N + TPB - 1) / TPB, TPB, 0, stream>>>(cnt0, 2 * N);
  count_kernel<<<gridE, TPB, 0, stream>>>(ei0 + E, ei1 + E, cnt0, cnt1, E);
  scan_kernel<<<2, 1024, 0, stream>>>(cnt0, off0, cnt1, off1, N);
  dinv_kernel<<<(N + TPB - 1) / TPB, TPB, 0, stream>>>(cnt0, cnt1, dinv0, dinv1, N);
  fill_kernel<<<gridE, TPB, 0, stream>>>(ei0, ei0 + E, ei1, ei1 + E,
                                         off0, off1, cnt0, cnt1, csr0, csr1, E);

  // --- GCN layers ---
  const float* hin = x;
  for (int i = 0; i < 3; i++) {
    mm_kernel<0><<<MMG, TPB, 0, stream>>>(hin, W0 + (size_t)i * D * D, nullptr, hW0, N);
    mm_kernel<0><<<MMG, TPB, 0, stream>>>(hin, W1 + (size_t)i * D * D, nullptr, hW1, N);
    gather_kernel<<<(N + 3) / 4, TPB, 0, stream>>>(hW0, hW1, dinv0, dinv1,
                                                   off0, csr0, off1, csr1,
                                                   b0 + i * D, b1 + i * D, hbuf, N);
    zero_f32_kernel<<<1, 256, 0, stream>>>(stats, 256);
    stats_kernel<<<200, TPB, 0, stream>>>(hbuf, stats, stats + 128, N, (N + 199) / 200);
    bn_coef_kernel<<<1, 128, 0, stream>>>(stats, stats + 128, gamma + i * D, beta + i * D,
                                          stats + 256, stats + 384, N);
    bn_apply_kernel<<<(N * 32 + TPB - 1) / TPB, TPB, 0, stream>>>(hbuf, stats + 256,
                                                                  stats + 384, N, i < 2 ? 1 : 0);
    hin = hbuf;
  }

  // --- heads ---
  mm_kernel<2><<<MMG, TPB, 0, stream>>>(hbuf, emb1_W, emb1_b, out, N);            // e1
  mm_kernel<3><<<MMG, TPB, 0, stream>>>(hbuf, emb2_W, emb2_b, out + ND, N);       // e2
  mm_kernel<1><<<MMG, TPB, 0, stream>>>(out, ph1_Wa, ph1_ba, hW1, N);             // t1
  mm_kernel<4><<<MMG, TPB, 0, stream>>>(hW1, ph1_Wb, ph1_bb, out + 2 * ND, N);    // p1
  mm_kernel<1><<<MMG, TPB, 0, stream>>>(out + ND, ph2_Wa, ph2_ba, hW1, N);        // t2
  mm_kernel<4><<<MMG, TPB, 0, stream>>>(hW1, ph2_Wb, ph2_bb, out + 3 * ND, N);    // p2
}

// Round 3
// 722.507 us; speedup vs baseline: 1.2375x; 1.2375x over previous
//
#include <hip/hip_runtime.h>
#include <cstdint>
#include <cstddef>

#define D 128

typedef __attribute__((ext_vector_type(8))) short bf16x8;
typedef __attribute__((ext_vector_type(4))) float f32x4;
typedef __attribute__((ext_vector_type(4))) _Float16 f16x4;
typedef __attribute__((ext_vector_type(2))) _Float16 f16x2;

__device__ __forceinline__ unsigned short f2bf(float f) {
  unsigned int u = __float_as_uint(f);
  unsigned int r = u + 0x7FFFu + ((u >> 16) & 1u);
  return (unsigned short)(r >> 16);
}
__device__ __forceinline__ float bf2f(unsigned short h) {
  return __uint_as_float((unsigned int)h << 16);
}

// ---------------- utility ----------------
__global__ void zero_i32_kernel(int* p, int n) {
  int i = blockIdx.x * blockDim.x + threadIdx.x;
  if (i < n) p[i] = 0;
}
__global__ void zero_f32_kernel(float* p, int n) {
  int i = blockIdx.x * blockDim.x + threadIdx.x;
  if (i < n) p[i] = 0.f;
}

// fp32 -> split bf16 hi/lo planes
__global__ void cvt_split_kernel(const float* __restrict__ src,
                                 unsigned short* __restrict__ hb, size_t np128,
                                 int total4) {
  int i = blockIdx.x * blockDim.x + threadIdx.x;
  if (i >= total4) return;
  float4 v = ((const float4*)src)[i];
  float vv[4] = {v.x, v.y, v.z, v.w};
  unsigned int h[4], l[4];
#pragma unroll
  for (int c = 0; c < 4; c++) {
    unsigned short hh = f2bf(vv[c]);
    h[c] = hh;
    l[c] = f2bf(vv[c] - bf2f(hh));
  }
  uint2 oh, ol;
  oh.x = h[0] | (h[1] << 16); oh.y = h[2] | (h[3] << 16);
  ol.x = l[0] | (l[1] << 16); ol.y = l[2] | (l[3] << 16);
  ((uint2*)hb)[i] = oh;
  ((uint2*)(hb + np128))[i] = ol;
}

// pack one 128x128 fp32 weight into per-lane MFMA A-operand fragments, hi+lo planes:
// frag[((jt*4+ks)*64+lane)*8 + b] = W[(ks*32 + (lane>>4)*8 + b)*128 + jt*16 + (lane&15)]
__global__ void pack_w_kernel(const float* __restrict__ W,
                              unsigned short* __restrict__ hi,
                              unsigned short* __restrict__ lo) {
  int tid = blockIdx.x * blockDim.x + threadIdx.x;  // 0..16383
  int b = tid & 7;
  int lane = (tid >> 3) & 63;
  int ks = (tid >> 9) & 3;
  int jt = tid >> 11;
  int k = ks * 32 + ((lane >> 4) << 3) + b;
  int j = jt * 16 + (lane & 15);
  float w = W[k * 128 + j];
  unsigned short h = f2bf(w);
  hi[tid] = h;
  lo[tid] = f2bf(w - bf2f(h));
}

// ---------------- CSR build ----------------
__global__ void count_kernel(const int* __restrict__ dst0, const int* __restrict__ dst1,
                             int* cnt0, int* cnt1, int E) {
  int e = blockIdx.x * blockDim.x + threadIdx.x;
  if (e < E) {
    atomicAdd(&cnt0[dst0[e]], 1);
    atomicAdd(&cnt1[dst1[e]], 1);
  }
}

__global__ __launch_bounds__(1024) void scan_kernel(const int* cnt0, int* off0,
                                                    const int* cnt1, int* off1, int n) {
  const int* cnt = (blockIdx.x == 0) ? cnt0 : cnt1;
  int* off = (blockIdx.x == 0) ? off0 : off1;
  __shared__ int tsum[1024];
  int tid = threadIdx.x;
  int per = (n + 1023) >> 10;
  int start = tid * per;
  int end = start + per; if (end > n) end = n;
  int s = 0;
  for (int i = start; i < end; i++) s += cnt[i];
  tsum[tid] = s;
  __syncthreads();
  for (int d = 1; d < 1024; d <<= 1) {
    int v = (tid >= d) ? tsum[tid - d] : 0;
    __syncthreads();
    if (tid >= d) tsum[tid] += v;
    __syncthreads();
  }
  int run = (tid > 0) ? tsum[tid - 1] : 0;
  for (int i = start; i < end; i++) { off[i] = run; run += cnt[i]; }
  if (tid == 1023) off[n] = run;
}

__global__ void dinv_kernel(int* cnt0, int* cnt1, float* dinv0, float* dinv1, int n) {
  int i = blockIdx.x * blockDim.x + threadIdx.x;
  if (i < n) {
    dinv0[i] = rsqrtf((float)cnt0[i] + 1.0f);
    dinv1[i] = rsqrtf((float)cnt1[i] + 1.0f);
    cnt0[i] = 0;
    cnt1[i] = 0;
  }
}

__global__ void fill_kernel(const int* __restrict__ src0, const int* __restrict__ dst0,
                            const int* __restrict__ src1, const int* __restrict__ dst1,
                            const int* __restrict__ off0, const int* __restrict__ off1,
                            int* cnt0, int* cnt1, int* csr0, int* csr1, int E) {
  int e = blockIdx.x * blockDim.x + threadIdx.x;
  if (e < E) {
    int d = dst0[e];
    int p = atomicAdd(&cnt0[d], 1);
    csr0[off0[d] + p] = src0[e];
    d = dst1[e];
    p = atomicAdd(&cnt1[d], 1);
    csr1[off1[d] + p] = src1[e];
  }
}

// ---------------- split-precision MFMA matmul (operand-swapped) ----------------
// acc[j][i] = bias[j] + sum_k W[k][j] * A[i][k], computed as Whi*Ahi + Wlo*Ahi + Whi*Alo.
// A: if AFP32, fp32 [n][128] split in-register; else bf16 hi plane + lo plane at +n*128.
// EPI: 0 = dual GCN fp16 tables (scale by dinv[src]); 1 = relu -> outb hi/lo planes;
//      2 = tanh -> outf; 3 = tanh+l2norm -> outf; 4 = l2norm -> outf
template <int NJT, int WJT, int WIT, int EPI, int AFP32>
__global__ __launch_bounds__(256) void mm_mfma(
    const unsigned short* __restrict__ Wph, const unsigned short* __restrict__ Wpl,
    const void* __restrict__ A, const float* __restrict__ bias,
    const float* __restrict__ dinv0, const float* __restrict__ dinv1,
    _Float16* __restrict__ tab0, _Float16* __restrict__ tab1,
    float* __restrict__ outf, unsigned short* __restrict__ outb, int n) {
  constexpr int JSPLIT = NJT / WJT;
  constexpr int ISPAN = (4 / JSPLIT) * WIT * 16;
  const size_t np128 = (size_t)n * 128;
  const int lane = threadIdx.x & 63;
  const int wid = threadIdx.x >> 6;
  const int wj = wid % JSPLIT, wi = wid / JSPLIT;
  const int jtbase = wj * WJT;
  const int ibase = blockIdx.x * ISPAN + wi * WIT * 16;
  const int lrow = lane & 15, lgrp = lane >> 4;

  const unsigned short* Ah = (const unsigned short*)A;
  const float* Af = (const float*)A;

  int node[WIT];
  bool valid[WIT];
#pragma unroll
  for (int it = 0; it < WIT; it++) {
    int i = ibase + it * 16 + lrow;
    valid[it] = (i < n);
    node[it] = valid[it] ? i : (n - 1);
  }

  f32x4 acc[WJT][WIT];
#pragma unroll
  for (int jt = 0; jt < WJT; jt++) {
    f32x4 bv = {0.f, 0.f, 0.f, 0.f};
    if (bias) {
      float4 b4 = *(const float4*)(bias + (jtbase + jt) * 16 + lgrp * 4);
      bv[0] = b4.x; bv[1] = b4.y; bv[2] = b4.z; bv[3] = b4.w;
    }
#pragma unroll
    for (int it = 0; it < WIT; it++) acc[jt][it] = bv;
  }

#pragma unroll
  for (int ks = 0; ks < 4; ks++) {
    bf16x8 awh[WJT], awl[WJT];
#pragma unroll
    for (int jt = 0; jt < WJT; jt++) {
      size_t fo = (size_t)(((jtbase + jt) * 4 + ks) * 64 + lane) * 8;
      awh[jt] = *(const bf16x8*)(Wph + fo);
      awl[jt] = *(const bf16x8*)(Wpl + fo);
    }
#pragma unroll
    for (int it = 0; it < WIT; it++) {
      bf16x8 bhh, bhl;
      if (AFP32) {
        const float* src = Af + (size_t)node[it] * 128 + ks * 32 + lgrp * 8;
        float4 u0 = *(const float4*)src;
        float4 u1 = *(const float4*)(src + 4);
        float vv[8] = {u0.x, u0.y, u0.z, u0.w, u1.x, u1.y, u1.z, u1.w};
#pragma unroll
        for (int c = 0; c < 8; c++) {
          unsigned short h = f2bf(vv[c]);
          bhh[c] = (short)h;
          bhl[c] = (short)f2bf(vv[c] - bf2f(h));
        }
      } else {
        size_t ao = (size_t)node[it] * 128 + ks * 32 + lgrp * 8;
        bhh = *(const bf16x8*)(Ah + ao);
        bhl = *(const bf16x8*)(Ah + np128 + ao);
      }
#pragma unroll
      for (int jt = 0; jt < WJT; jt++) {
        acc[jt][it] = __builtin_amdgcn_mfma_f32_16x16x32_bf16(awh[jt], bhh, acc[jt][it], 0, 0, 0);
        acc[jt][it] = __builtin_amdgcn_mfma_f32_16x16x32_bf16(awl[jt], bhh, acc[jt][it], 0, 0, 0);
        acc[jt][it] = __builtin_amdgcn_mfma_f32_16x16x32_bf16(awh[jt], bhl, acc[jt][it], 0, 0, 0);
      }
    }
  }

  if (EPI == 1) {
#pragma unroll
    for (int jt = 0; jt < WJT; jt++)
#pragma unroll
      for (int it = 0; it < WIT; it++)
#pragma unroll
        for (int c = 0; c < 4; c++) acc[jt][it][c] = fmaxf(acc[jt][it][c], 0.f);
  }
  if (EPI == 2 || EPI == 3) {
#pragma unroll
    for (int jt = 0; jt < WJT; jt++)
#pragma unroll
      for (int it = 0; it < WIT; it++)
#pragma unroll
        for (int c = 0; c < 4; c++) acc[jt][it][c] = tanhf(acc[jt][it][c]);
  }
  if (EPI == 3 || EPI == 4) {
#pragma unroll
    for (int it = 0; it < WIT; it++) {
      float rs = 0.f;
#pragma unroll
      for (int jt = 0; jt < WJT; jt++)
#pragma unroll
        for (int c = 0; c < 4; c++) rs += acc[jt][it][c] * acc[jt][it][c];
      rs += __shfl_xor(rs, 16);
      rs += __shfl_xor(rs, 32);
      float scl = 1.f / fmaxf(sqrtf(rs), 1e-12f);
#pragma unroll
      for (int jt = 0; jt < WJT; jt++)
#pragma unroll
        for (int c = 0; c < 4; c++) acc[jt][it][c] *= scl;
    }
  }

  if (EPI == 0) {
#pragma unroll
    for (int it = 0; it < WIT; it++) {
      if (!valid[it]) continue;
      float d0v = dinv0[node[it]];
      float d1v = dinv1[node[it]];
#pragma unroll
      for (int jt = 0; jt < WJT; jt++) {
        int jg = jtbase + jt;
        float s = (jg < 8) ? d0v : d1v;
        f16x4 o;
#pragma unroll
        for (int c = 0; c < 4; c++) o[c] = (_Float16)(acc[jt][it][c] * s);
        _Float16* base = (jg < 8)
            ? (tab0 + (size_t)node[it] * 128 + jg * 16)
            : (tab1 + (size_t)node[it] * 128 + (jg - 8) * 16);
        *(f16x4*)(base + lgrp * 4) = o;
      }
    }
  } else if (EPI == 1) {
#pragma unroll
    for (int it = 0; it < WIT; it++) {
      if (!valid[it]) continue;
#pragma unroll
      for (int jt = 0; jt < WJT; jt++) {
        int j0 = (jtbase + jt) * 16 + lgrp * 4;
        unsigned int h[4], l[4];
#pragma unroll
        for (int c = 0; c < 4; c++) {
          unsigned short hh = f2bf(acc[jt][it][c]);
          h[c] = hh;
          l[c] = f2bf(acc[jt][it][c] - bf2f(hh));
        }
        uint2 oh, ol;
        oh.x = h[0] | (h[1] << 16); oh.y = h[2] | (h[3] << 16);
        ol.x = l[0] | (l[1] << 16); ol.y = l[2] | (l[3] << 16);
        size_t ao = (size_t)node[it] * 128 + j0;
        *(uint2*)(outb + ao) = oh;
        *(uint2*)(outb + np128 + ao) = ol;
      }
    }
  } else {
#pragma unroll
    for (int it = 0; it < WIT; it++) {
      if (!valid[it]) continue;
#pragma unroll
      for (int jt = 0; jt < WJT; jt++) {
        int j0 = (jtbase + jt) * 16 + lgrp * 4;
        *(float4*)(outf + (size_t)node[it] * 128 + j0) =
            make_float4(acc[jt][it][0], acc[jt][it][1], acc[jt][it][2], acc[jt][it][3]);
      }
    }
  }
}

// ---------------- aggregation (gather over fp16 pre-scaled tables) ----------------
__global__ __launch_bounds__(256) void gather_kernel(
    const _Float16* __restrict__ tab0, const _Float16* __restrict__ tab1,
    const float* __restrict__ dinv0, const float* __restrict__ dinv1,
    const int* __restrict__ off0, const int* __restrict__ csr0,
    const int* __restrict__ off1, const int* __restrict__ csr1,
    const float* __restrict__ b0, const float* __restrict__ b1,
    float* __restrict__ outh, int n) {
  int warp = threadIdx.x >> 6;
  int lane = threadIdx.x & 63;
  int node = blockIdx.x * 4 + warp;
  if (node >= n) return;
  const f16x2* t0 = (const f16x2*)tab0;
  const f16x2* t1 = (const f16x2*)tab1;
  // self row first (self-loop folds into the scaled sum)
  f16x2 v = t0[(size_t)node * 64 + lane];
  float s0x = (float)v[0], s0y = (float)v[1];
  v = t1[(size_t)node * 64 + lane];
  float s1x = (float)v[0], s1y = (float)v[1];
  int a = off0[node], b = off0[node + 1];
  for (int j = a; j < b; j++) {
    int s = csr0[j];
    v = t0[(size_t)s * 64 + lane];
    s0x += (float)v[0]; s0y += (float)v[1];
  }
  a = off1[node]; b = off1[node + 1];
  for (int j = a; j < b; j++) {
    int s = csr1[j];
    v = t1[(size_t)s * 64 + lane];
    s1x += (float)v[0]; s1y += (float)v[1];
  }
  float d0 = dinv0[node], d1 = dinv1[node];
  float2 B0 = ((const float2*)b0)[lane];
  float2 B1 = ((const float2*)b1)[lane];
  float2 r;
  r.x = d0 * s0x + d1 * s1x + B0.x + B1.x;
  r.y = d0 * s0y + d1 * s1y + B0.y + B1.y;
  ((float2*)outh)[(size_t)node * 64 + lane] = r;
}

// ---------------- BatchNorm ----------------
__global__ __launch_bounds__(256) void stats_kernel(const float* __restrict__ h,
                                                    float* colsum, float* colsumsq,
                                                    int n, int rpb) {
  int col = threadIdx.x & 127;
  int sub = threadIdx.x >> 7;
  int r0 = blockIdx.x * rpb;
  int r1 = r0 + rpb; if (r1 > n) r1 = n;
  float s = 0.f, ss = 0.f;
  for (int r = r0 + sub; r < r1; r += 2) {
    float v = h[(size_t)r * D + col];
    s += v; ss += v * v;
  }
  __shared__ float ls[256], lss[256];
  ls[threadIdx.x] = s; lss[threadIdx.x] = ss;
  __syncthreads();
  if (sub == 0) {
    s += ls[threadIdx.x + 128];
    ss += lss[threadIdx.x + 128];
    atomicAdd(&colsum[col], s);
    atomicAdd(&colsumsq[col], ss);
  }
}

__global__ void bn_coef_kernel(const float* colsum, const float* colsumsq,
                               const float* __restrict__ g, const float* __restrict__ bt,
                               float* colscale, float* colshift, int n) {
  int c = threadIdx.x;
  if (c < D) {
    float invn = 1.0f / (float)n;
    float mu = colsum[c] * invn;
    float var = colsumsq[c] * invn - mu * mu;
    float sc = g[c] * rsqrtf(var + 1e-5f);
    colscale[c] = sc;
    colshift[c] = bt[c] - mu * sc;
  }
}

// BN apply + optional relu, writing split bf16 hi/lo planes (next matmul's A)
__global__ void bn_apply_split_kernel(const float* __restrict__ h,
                                      const float* __restrict__ colscale,
                                      const float* __restrict__ colshift,
                                      unsigned short* __restrict__ hb, size_t np128,
                                      int n, int relu) {
  int idx = blockIdx.x * blockDim.x + threadIdx.x;
  int total = n * 32;
  if (idx >= total) return;
  int r = idx >> 5;
  int c4 = (idx & 31) * 4;
  float4 vv = *(const float4*)(h + (size_t)r * D + c4);
  float4 sc = *(const float4*)(colscale + c4);
  float4 sh = *(const float4*)(colshift + c4);
  float o[4];
  o[0] = vv.x * sc.x + sh.x;
  o[1] = vv.y * sc.y + sh.y;
  o[2] = vv.z * sc.z + sh.z;
  o[3] = vv.w * sc.w + sh.w;
  if (relu) {
#pragma unroll
    for (int c = 0; c < 4; c++) o[c] = fmaxf(o[c], 0.f);
  }
  unsigned int hh[4], ll[4];
#pragma unroll
  for (int c = 0; c < 4; c++) {
    unsigned short x = f2bf(o[c]);
    hh[c] = x;
    ll[c] = f2bf(o[c] - bf2f(x));
  }
  uint2 oh, ol;
  oh.x = hh[0] | (hh[1] << 16); oh.y = hh[2] | (hh[3] << 16);
  ol.x = ll[0] | (ll[1] << 16); ol.y = ll[2] | (ll[3] << 16);
  ((uint2*)hb)[idx] = oh;
  ((uint2*)(hb + np128))[idx] = ol;
}

// ---------------- launch ----------------
extern "C" void kernel_launch(void* const* d_in, const int* in_sizes, int n_in,
                              void* d_out, int out_size, void* d_ws, size_t ws_size,
                              hipStream_t stream) {
  const float* x      = (const float*)d_in[0];
  const int*   ei0    = (const int*)d_in[1];
  const int*   ei1    = (const int*)d_in[2];
  const float* W0     = (const float*)d_in[3];
  const float* b0     = (const float*)d_in[4];
  const float* W1     = (const float*)d_in[5];
  const float* b1     = (const float*)d_in[6];
  const float* gamma  = (const float*)d_in[7];
  const float* beta   = (const float*)d_in[8];
  const float* emb1_W = (const float*)d_in[9];
  const float* emb1_b = (const float*)d_in[10];
  const float* emb2_W = (const float*)d_in[11];
  const float* emb2_b = (const float*)d_in[12];
  const float* ph1_Wa = (const float*)d_in[13];
  const float* ph1_ba = (const float*)d_in[14];
  const float* ph1_Wb = (const float*)d_in[15];
  const float* ph1_bb = (const float*)d_in[16];
  const float* ph2_Wa = (const float*)d_in[17];
  const float* ph2_ba = (const float*)d_in[18];
  const float* ph2_Wb = (const float*)d_in[19];
  const float* ph2_bb = (const float*)d_in[20];

  const int N = in_sizes[0] / D;
  const int E = in_sizes[1] / 2;
  const size_t ND = (size_t)N * D;
  float* out = (float*)d_out;

  char* p = (char*)d_ws;
  char* pend = p + ws_size;
  auto carve = [&](size_t bytes) -> void* {
    void* r = (void*)p;
    p += (bytes + 255) & ~(size_t)255;
    return r;
  };
  int*   cnt0  = (int*)carve((size_t)2 * N * 4);
  int*   cnt1  = cnt0 + N;
  int*   off0  = (int*)carve((size_t)(N + 1) * 4);
  int*   off1  = (int*)carve((size_t)(N + 1) * 4);
  float* dinv0 = (float*)carve((size_t)N * 4);
  float* dinv1 = (float*)carve((size_t)N * 4);
  int*   csr0  = (int*)carve((size_t)E * 4);
  int*   csr1  = (int*)carve((size_t)E * 4);
  float* stats = (float*)carve(512 * 4);
  // packed weights: dual layers 3 x (hi 32768 + lo 32768), heads 6 x (hi 16384 + lo 16384)
  unsigned short* WpD = (unsigned short*)carve((size_t)3 * 65536 * 2);
  unsigned short* WpH = (unsigned short*)carve((size_t)6 * 32768 * 2);

  // big buffers
  float* hbuf = out + 2 * ND;                  // fp32 gather output, p1 slot (dead before p1 write)
  unsigned short* hBp;                          // A-plane pair (hi, lo at +ND)
  _Float16 *tab0, *tab1;
  size_t avail = (size_t)(pend - p);
  if (avail >= 8 * ND + 1024) {
    hBp  = (unsigned short*)carve(4 * ND);      // 2 planes x 2B
    tab0 = (_Float16*)carve(2 * ND);
    tab1 = (_Float16*)carve(2 * ND);
  } else {
    hBp  = (unsigned short*)carve(4 * ND);
    tab0 = (_Float16*)(out + 3 * ND);           // p2 slot (dead until p2 write, which is last)
    tab1 = tab0 + ND;
  }
  unsigned short* tb = hBp;                     // reused for relu intermediates after heads consume hB

  const int TPB = 256;
  const int gridE = (E + TPB - 1) / TPB;
  const int gridDual = (N + 63) / 64;
  const int gridHead = (N + 127) / 128;

  // --- weight packing + x split ---
  for (int i = 0; i < 3; i++) {
    unsigned short* base = WpD + (size_t)i * 65536;
    pack_w_kernel<<<64, TPB, 0, stream>>>(W0 + (size_t)i * D * D, base, base + 32768);
    pack_w_kernel<<<64, TPB, 0, stream>>>(W1 + (size_t)i * D * D, base + 16384, base + 49152);
  }
  const float* headW[6] = {emb1_W, emb2_W, ph1_Wa, ph1_Wb, ph2_Wa, ph2_Wb};
  for (int i = 0; i < 6; i++) {
    unsigned short* base = WpH + (size_t)i * 32768;
    pack_w_kernel<<<64, TPB, 0, stream>>>(headW[i], base, base + 16384);
  }
  cvt_split_kernel<<<(N * 32 + TPB - 1) / TPB, TPB, 0, stream>>>(x, hBp, ND, N * 32);

  // --- CSR build ---
  zero_i32_kernel<<<(2 * N + TPB - 1) / TPB, TPB, 0, stream>>>(cnt0, 2 * N);
  count_kernel<<<gridE, TPB, 0, stream>>>(ei0 + E, ei1 + E, cnt0, cnt1, E);
  scan_kernel<<<2, 1024, 0, stream>>>(cnt0, off0, cnt1, off1, N);
  dinv_kernel<<<(N + TPB - 1) / TPB, TPB, 0, stream>>>(cnt0, cnt1, dinv0, dinv1, N);
  fill_kernel<<<gridE, TPB, 0, stream>>>(ei0, ei0 + E, ei1, ei1 + E,
                                         off0, off1, cnt0, cnt1, csr0, csr1, E);

  // --- GCN layers ---
  for (int i = 0; i < 3; i++) {
    unsigned short* wb = WpD + (size_t)i * 65536;
    mm_mfma<16, 4, 4, 0, 0><<<gridDual, TPB, 0, stream>>>(
        wb, wb + 32768, hBp, nullptr, dinv0, dinv1, tab0, tab1, nullptr, nullptr, N);
    gather_kernel<<<(N + 3) / 4, TPB, 0, stream>>>(tab0, tab1, dinv0, dinv1,
                                                   off0, csr0, off1, csr1,
                                                   b0 + i * D, b1 + i * D, hbuf, N);
    zero_f32_kernel<<<1, 256, 0, stream>>>(stats, 256);
    stats_kernel<<<200, TPB, 0, stream>>>(hbuf, stats, stats + 128, N, (N + 199) / 200);
    bn_coef_kernel<<<1, 128, 0, stream>>>(stats, stats + 128, gamma + i * D, beta + i * D,
                                          stats + 256, stats + 384, N);
    bn_apply_split_kernel<<<(N * 32 + TPB - 1) / TPB, TPB, 0, stream>>>(
        hbuf, stats + 256, stats + 384, hBp, ND, N, i < 2 ? 1 : 0);
  }

  // --- heads ---
  // e1 = tanh(h@emb1W+b) -> out0
  mm_mfma<8, 8, 2, 2, 0><<<gridHead, TPB, 0, stream>>>(
      WpH, WpH + 16384, hBp, emb1_b, nullptr, nullptr, nullptr, nullptr, out, nullptr, N);
  // e2 = l2norm(tanh(h@emb2W+b)) -> out1
  mm_mfma<8, 8, 2, 3, 0><<<gridHead, TPB, 0, stream>>>(
      WpH + 32768, WpH + 49152, hBp, emb2_b, nullptr, nullptr, nullptr, nullptr, out + ND, nullptr, N);
  // t1 = relu(e1@ph1_Wa+ba) -> tb planes (reads exact fp32 e1 from out0)
  mm_mfma<8, 8, 2, 1, 1><<<gridHead, TPB, 0, stream>>>(
      WpH + 65536, WpH + 81920, out, ph1_ba, nullptr, nullptr, nullptr, nullptr, nullptr, tb, N);
  // p1 = l2norm(t1@ph1_Wb+bb) -> out2
  mm_mfma<8, 8, 2, 4, 0><<<gridHead, TPB, 0, stream>>>(
      WpH + 98304, WpH + 114688, tb, ph1_bb, nullptr, nullptr, nullptr, nullptr, out + 2 * ND, nullptr, N);
  // t2 = relu(e2@ph2_Wa+ba) -> tb planes (reads exact fp32 e2 from out1)
  mm_mfma<8, 8, 2, 1, 1><<<gridHead, TPB, 0, stream>>>(
      WpH + 131072, WpH + 147456, out + ND, ph2_ba, nullptr, nullptr, nullptr, nullptr, nullptr, tb, N);
  // p2 = l2norm(t2@ph2_Wb+bb) -> out3
  mm_mfma<8, 8, 2, 4, 0><<<gridHead, TPB, 0, stream>>>(
      WpH + 163840, WpH + 180224, tb, ph2_bb, nullptr, nullptr, nullptr, nullptr, out + 3 * ND, nullptr, N);
}

// Round 4
// 522.801 us; speedup vs baseline: 1.7102x; 1.3820x over previous
//
#include <hip/hip_runtime.h>
#include <cstdint>
#include <cstddef>

#define D 128

typedef __attribute__((ext_vector_type(8))) short bf16x8;
typedef __attribute__((ext_vector_type(4))) float f32x4;
typedef __attribute__((ext_vector_type(4))) _Float16 f16x4;
typedef __attribute__((ext_vector_type(8))) _Float16 f16x8;

__device__ __forceinline__ unsigned short f2bf(float f) {
  unsigned int u = __float_as_uint(f);
  unsigned int r = u + 0x7FFFu + ((u >> 16) & 1u);
  return (unsigned short)(r >> 16);
}
__device__ __forceinline__ float bf2f(unsigned short h) {
  return __uint_as_float((unsigned int)h << 16);
}

// ---------------- weight packing (all 12 matrices in one launch) ----------------
// per-lane MFMA A-operand fragments, hi plane + lo (residual) plane:
// slot m: hi[r] at Wp[m*32768 + r], lo[r] at Wp[m*32768 + 16384 + r]
// r = ((jt*4+ks)*64+lane)*8 + b  ->  W[(ks*32+(lane>>4)*8+b)*128 + jt*16+(lane&15)]
struct WPtrs { const float* w[12]; };

__global__ __launch_bounds__(256) void pack_all_kernel(WPtrs P, unsigned short* __restrict__ Wp) {
  int tid = blockIdx.x * blockDim.x + threadIdx.x;  // 0..196607
  int m = tid >> 14;
  int r = tid & 16383;
  int b = r & 7, lane = (r >> 3) & 63, ks = (r >> 9) & 3, jt = r >> 11;
  int k = ks * 32 + ((lane >> 4) << 3) + b;
  int j = jt * 16 + (lane & 15);
  float w = P.w[m][k * 128 + j];
  unsigned short h = f2bf(w);
  Wp[m * 32768 + r] = h;
  Wp[m * 32768 + 16384 + r] = f2bf(w - bf2f(h));
}

// ---------------- CSR build (concatenated: type0 = [0,N), type1 = [N,2N)) ----------------
__global__ void count_kernel(const int* __restrict__ d0, const int* __restrict__ d1,
                             int* __restrict__ cnt, int E, int N) {
  int e = blockIdx.x * blockDim.x + threadIdx.x;
  if (e < E) {
    atomicAdd(&cnt[d0[e]], 1);
    atomicAdd(&cnt[N + d1[e]], 1);
  }
}

// phase 1: per-block (512 elems) exclusive scan + block totals
__global__ __launch_bounds__(256) void scan_part_kernel(const int* __restrict__ cnt,
                                                        int* __restrict__ off,
                                                        int* __restrict__ bsum, int n2) {
  __shared__ int sh[256];
  int t = threadIdx.x;
  int i0 = blockIdx.x * 512 + 2 * t;
  int a0 = (i0 < n2) ? cnt[i0] : 0;
  int a1 = (i0 + 1 < n2) ? cnt[i0 + 1] : 0;
  int s = a0 + a1;
  sh[t] = s;
  __syncthreads();
  for (int d = 1; d < 256; d <<= 1) {
    int v = (t >= d) ? sh[t - d] : 0;
    __syncthreads();
    sh[t] += v;
    __syncthreads();
  }
  int p = sh[t] - s;  // exclusive prefix within block
  if (i0 < n2) off[i0] = p;
  if (i0 + 1 < n2) off[i0 + 1] = p + a0;
  if (t == 255) bsum[blockIdx.x] = sh[255];
}

// phase 2: scan block sums (nb <= 256), write grand total to off[n2]
__global__ __launch_bounds__(256) void scan_bsum_kernel(int* __restrict__ bsum, int nb,
                                                        int* __restrict__ off_total) {
  __shared__ int sh[256];
  int t = threadIdx.x;
  int s = (t < nb) ? bsum[t] : 0;
  sh[t] = s;
  __syncthreads();
  for (int d = 1; d < 256; d <<= 1) {
    int v = (t >= d) ? sh[t - d] : 0;
    __syncthreads();
    sh[t] += v;
    __syncthreads();
  }
  if (t < nb) bsum[t] = sh[t] - s;
  if (t == 255) *off_total = sh[255];
}

// phase 3: add block prefixes; fold in dinv compute + cursor zeroing
__global__ __launch_bounds__(256) void scan_add_kernel(int* __restrict__ off,
                                                       const int* __restrict__ bsum,
                                                       int* __restrict__ cnt,
                                                       float* __restrict__ dinv, int n2) {
  int add = bsum[blockIdx.x];
  int base = blockIdx.x * 512;
#pragma unroll
  for (int u = 0; u < 2; u++) {
    int i = base + threadIdx.x + u * 256;
    if (i < n2) {
      off[i] += add;
      dinv[i] = rsqrtf((float)cnt[i] + 1.0f);
      cnt[i] = 0;
    }
  }
}

__global__ void fill_kernel(const int* __restrict__ ei0, const int* __restrict__ ei1,
                            const int* __restrict__ off, int* __restrict__ cnt,
                            int* __restrict__ csr, int E, int N) {
  int e = blockIdx.x * blockDim.x + threadIdx.x;
  if (e < E) {
    int s = ei0[e], d = ei0[E + e];
    int p = atomicAdd(&cnt[d], 1);
    csr[off[d] + p] = s;
    s = ei1[e]; d = ei1[E + e];
    p = atomicAdd(&cnt[N + d], 1);
    csr[off[N + d] + p] = s;
  }
}

// ---------------- split-precision MFMA matmul (operand-swapped) ----------------
// acc[j][i] = bias[j] + sum_k W[k][j]*A[i][k]   via  Whi*Ahi + Wlo*Ahi + Whi*Alo
// A is fp32 [n][128]; BN: 0=none, 1=scale/shift+relu, 2=scale/shift (applied to A in-register)
// EPI: 0 = dual GCN fp16 tables (scale by dinv[src], jt<8 -> tab0, else tab1)
//      1 = relu -> outf ; 2 = tanh -> outf ; 3 = tanh+l2norm -> outf ; 4 = l2norm -> outf
template <int NJT, int WJT, int WIT, int EPI, int BN>
__global__ __launch_bounds__(256) void mm_mfma(
    const unsigned short* __restrict__ Wp, const float* __restrict__ Af,
    const float* __restrict__ bnsc, const float* __restrict__ bnsh,
    const float* __restrict__ bias, const float* __restrict__ dinv,
    _Float16* __restrict__ tab0, _Float16* __restrict__ tab1,
    float* __restrict__ outf, int n, int N) {
  constexpr int JSPLIT = NJT / WJT;
  constexpr int ISPAN = (4 / JSPLIT) * WIT * 16;
  const int lane = threadIdx.x & 63;
  const int wid = threadIdx.x >> 6;
  const int wj = wid % JSPLIT, wi = wid / JSPLIT;
  const int jtbase = wj * WJT;
  const int ibase = blockIdx.x * ISPAN + wi * WIT * 16;
  const int lrow = lane & 15, lgrp = lane >> 4;

  int node[WIT];
  bool valid[WIT];
#pragma unroll
  for (int it = 0; it < WIT; it++) {
    int i = ibase + it * 16 + lrow;
    valid[it] = (i < n);
    node[it] = valid[it] ? i : (n - 1);
  }

  f32x4 acc[WJT][WIT];
#pragma unroll
  for (int jt = 0; jt < WJT; jt++) {
    f32x4 bv = {0.f, 0.f, 0.f, 0.f};
    if (bias) {
      float4 b4 = *(const float4*)(bias + (jtbase + jt) * 16 + lgrp * 4);
      bv[0] = b4.x; bv[1] = b4.y; bv[2] = b4.z; bv[3] = b4.w;
    }
#pragma unroll
    for (int it = 0; it < WIT; it++) acc[jt][it] = bv;
  }

#pragma unroll
  for (int ks = 0; ks < 4; ks++) {
    float sck[8], shk[8];
    if (BN) {
      float4 s0 = *(const float4*)(bnsc + ks * 32 + lgrp * 8);
      float4 s1 = *(const float4*)(bnsc + ks * 32 + lgrp * 8 + 4);
      float4 h0 = *(const float4*)(bnsh + ks * 32 + lgrp * 8);
      float4 h1 = *(const float4*)(bnsh + ks * 32 + lgrp * 8 + 4);
      sck[0]=s0.x; sck[1]=s0.y; sck[2]=s0.z; sck[3]=s0.w;
      sck[4]=s1.x; sck[5]=s1.y; sck[6]=s1.z; sck[7]=s1.w;
      shk[0]=h0.x; shk[1]=h0.y; shk[2]=h0.z; shk[3]=h0.w;
      shk[4]=h1.x; shk[5]=h1.y; shk[6]=h1.z; shk[7]=h1.w;
    }
    bf16x8 awh[WJT], awl[WJT];
#pragma unroll
    for (int jt = 0; jt < WJT; jt++) {
      int jg = jtbase + jt;
      const unsigned short* base = Wp + ((NJT == 16 && jg >= 8) ? 32768 : 0);
      size_t fo = (size_t)(((jg & 7) * 4 + ks) * 64 + lane) * 8;
      awh[jt] = *(const bf16x8*)(base + fo);
      awl[jt] = *(const bf16x8*)(base + fo + 16384);
    }
#pragma unroll
    for (int it = 0; it < WIT; it++) {
      const float* src = Af + (size_t)node[it] * 128 + ks * 32 + lgrp * 8;
      float4 u0 = *(const float4*)src;
      float4 u1 = *(const float4*)(src + 4);
      float vv[8] = {u0.x, u0.y, u0.z, u0.w, u1.x, u1.y, u1.z, u1.w};
      if (BN) {
#pragma unroll
        for (int c = 0; c < 8; c++) {
          vv[c] = vv[c] * sck[c] + shk[c];
          if (BN == 1) vv[c] = fmaxf(vv[c], 0.f);
        }
      }
      bf16x8 bhh, bhl;
#pragma unroll
      for (int c = 0; c < 8; c++) {
        unsigned short h = f2bf(vv[c]);
        bhh[c] = (short)h;
        bhl[c] = (short)f2bf(vv[c] - bf2f(h));
      }
#pragma unroll
      for (int jt = 0; jt < WJT; jt++) {
        acc[jt][it] = __builtin_amdgcn_mfma_f32_16x16x32_bf16(awh[jt], bhh, acc[jt][it], 0, 0, 0);
        acc[jt][it] = __builtin_amdgcn_mfma_f32_16x16x32_bf16(awl[jt], bhh, acc[jt][it], 0, 0, 0);
        acc[jt][it] = __builtin_amdgcn_mfma_f32_16x16x32_bf16(awh[jt], bhl, acc[jt][it], 0, 0, 0);
      }
    }
  }

  if (EPI == 1) {
#pragma unroll
    for (int jt = 0; jt < WJT; jt++)
#pragma unroll
      for (int it = 0; it < WIT; it++)
#pragma unroll
        for (int c = 0; c < 4; c++) acc[jt][it][c] = fmaxf(acc[jt][it][c], 0.f);
  }
  if (EPI == 2 || EPI == 3) {
#pragma unroll
    for (int jt = 0; jt < WJT; jt++)
#pragma unroll
      for (int it = 0; it < WIT; it++)
#pragma unroll
        for (int c = 0; c < 4; c++) acc[jt][it][c] = tanhf(acc[jt][it][c]);
  }
  if (EPI == 3 || EPI == 4) {
#pragma unroll
    for (int it = 0; it < WIT; it++) {
      float rs = 0.f;
#pragma unroll
      for (int jt = 0; jt < WJT; jt++)
#pragma unroll
        for (int c = 0; c < 4; c++) rs += acc[jt][it][c] * acc[jt][it][c];
      rs += __shfl_xor(rs, 16);
      rs += __shfl_xor(rs, 32);
      float scl = 1.f / fmaxf(sqrtf(rs), 1e-12f);
#pragma unroll
      for (int jt = 0; jt < WJT; jt++)
#pragma unroll
        for (int c = 0; c < 4; c++) acc[jt][it][c] *= scl;
    }
  }

  if (EPI == 0) {
#pragma unroll
    for (int it = 0; it < WIT; it++) {
      if (!valid[it]) continue;
      float d0v = dinv[node[it]];
      float d1v = dinv[N + node[it]];
#pragma unroll
      for (int jt = 0; jt < WJT; jt++) {
        int jg = jtbase + jt;
        float s = (jg < 8) ? d0v : d1v;
        f16x4 o;
#pragma unroll
        for (int c = 0; c < 4; c++) o[c] = (_Float16)(acc[jt][it][c] * s);
        _Float16* base = (jg < 8)
            ? (tab0 + (size_t)node[it] * 128 + jg * 16)
            : (tab1 + (size_t)node[it] * 128 + (jg - 8) * 16);
        *(f16x4*)(base + lgrp * 4) = o;
      }
    }
  } else {
#pragma unroll
    for (int it = 0; it < WIT; it++) {
      if (!valid[it]) continue;
#pragma unroll
      for (int jt = 0; jt < WJT; jt++) {
        int j0 = (jtbase + jt) * 16 + lgrp * 4;
        *(float4*)(outf + (size_t)node[it] * 128 + j0) =
            make_float4(acc[jt][it][0], acc[jt][it][1], acc[jt][it][2], acc[jt][it][3]);
      }
    }
  }
}

// ---------------- aggregation: 16-lane group per node, f16x8 (16B) per lane ----------------
__global__ __launch_bounds__(256) void gather_kernel(
    const _Float16* __restrict__ tab0, const _Float16* __restrict__ tab1,
    const float* __restrict__ dinv, const int* __restrict__ off,
    const int* __restrict__ csr,
    const float* __restrict__ b0, const float* __restrict__ b1,
    float* __restrict__ outh, int n, int N) {
  int g = threadIdx.x >> 4;
  int l = threadIdx.x & 15;
  int node = blockIdx.x * 16 + g;
  if (node >= n) return;
  const f16x8* t0 = (const f16x8*)tab0;
  const f16x8* t1 = (const f16x8*)tab1;
  float s0[8], s1[8];
  f16x8 v = t0[(size_t)node * 16 + l];  // self row (self-loop folds into scaled sum)
#pragma unroll
  for (int c = 0; c < 8; c++) s0[c] = (float)v[c];
  v = t1[(size_t)node * 16 + l];
#pragma unroll
  for (int c = 0; c < 8; c++) s1[c] = (float)v[c];
  int a = off[node], b = off[node + 1];
  for (int j = a; j < b; j++) {
    int s = csr[j];
    f16x8 vv = t0[(size_t)s * 16 + l];
#pragma unroll
    for (int c = 0; c < 8; c++) s0[c] += (float)vv[c];
  }
  a = off[N + node]; b = off[N + node + 1];
  for (int j = a; j < b; j++) {
    int s = csr[j];
    f16x8 vv = t1[(size_t)s * 16 + l];
#pragma unroll
    for (int c = 0; c < 8; c++) s1[c] += (float)vv[c];
  }
  float d0 = dinv[node], d1 = dinv[N + node];
  float4 ba0 = *(const float4*)(b0 + l * 8);
  float4 ba1 = *(const float4*)(b0 + l * 8 + 4);
  float4 bb0 = *(const float4*)(b1 + l * 8);
  float4 bb1 = *(const float4*)(b1 + l * 8 + 4);
  float bs[8] = {ba0.x + bb0.x, ba0.y + bb0.y, ba0.z + bb0.z, ba0.w + bb0.w,
                 ba1.x + bb1.x, ba1.y + bb1.y, ba1.z + bb1.z, ba1.w + bb1.w};
  float o[8];
#pragma unroll
  for (int c = 0; c < 8; c++) o[c] = d0 * s0[c] + d1 * s1[c] + bs[c];
  float* dst = outh + (size_t)node * 128 + l * 8;
  *(float4*)dst = make_float4(o[0], o[1], o[2], o[3]);
  *(float4*)(dst + 4) = make_float4(o[4], o[5], o[6], o[7]);
}

// ---------------- BatchNorm stats + coefs ----------------
__global__ __launch_bounds__(256) void stats_kernel(const float* __restrict__ h,
                                                    float* colsum, float* colsumsq,
                                                    int n, int rpb) {
  int col = threadIdx.x & 127;
  int sub = threadIdx.x >> 7;
  int r0 = blockIdx.x * rpb;
  int r1 = r0 + rpb; if (r1 > n) r1 = n;
  float s = 0.f, ss = 0.f;
  for (int r = r0 + sub; r < r1; r += 2) {
    float v = h[(size_t)r * D + col];
    s += v; ss += v * v;
  }
  __shared__ float ls[256], lss[256];
  ls[threadIdx.x] = s; lss[threadIdx.x] = ss;
  __syncthreads();
  if (sub == 0) {
    s += ls[threadIdx.x + 128];
    ss += lss[threadIdx.x + 128];
    atomicAdd(&colsum[col], s);
    atomicAdd(&colsumsq[col], ss);
  }
}

__global__ void bn_coef_kernel(const float* colsum, const float* colsumsq,
                               const float* __restrict__ g, const float* __restrict__ bt,
                               float* colscale, float* colshift, int n) {
  int c = threadIdx.x;
  if (c < D) {
    float invn = 1.0f / (float)n;
    float mu = colsum[c] * invn;
    float var = colsumsq[c] * invn - mu * mu;
    float sc = g[c] * rsqrtf(var + 1e-5f);
    colscale[c] = sc;
    colshift[c] = bt[c] - mu * sc;
  }
}

// ---------------- launch ----------------
extern "C" void kernel_launch(void* const* d_in, const int* in_sizes, int n_in,
                              void* d_out, int out_size, void* d_ws, size_t ws_size,
                              hipStream_t stream) {
  const float* x      = (const float*)d_in[0];
  const int*   ei0    = (const int*)d_in[1];
  const int*   ei1    = (const int*)d_in[2];
  const float* W0     = (const float*)d_in[3];
  const float* b0     = (const float*)d_in[4];
  const float* W1     = (const float*)d_in[5];
  const float* b1     = (const float*)d_in[6];
  const float* gamma  = (const float*)d_in[7];
  const float* beta   = (const float*)d_in[8];
  const float* emb1_W = (const float*)d_in[9];
  const float* emb1_b = (const float*)d_in[10];
  const float* emb2_W = (const float*)d_in[11];
  const float* emb2_b = (const float*)d_in[12];
  const float* ph1_Wa = (const float*)d_in[13];
  const float* ph1_ba = (const float*)d_in[14];
  const float* ph1_Wb = (const float*)d_in[15];
  const float* ph1_bb = (const float*)d_in[16];
  const float* ph2_Wa = (const float*)d_in[17];
  const float* ph2_ba = (const float*)d_in[18];
  const float* ph2_Wb = (const float*)d_in[19];
  const float* ph2_bb = (const float*)d_in[20];

  const int N = in_sizes[0] / D;
  const int E = in_sizes[1] / 2;
  const int N2 = 2 * N;
  const size_t ND = (size_t)N * D;
  float* out = (float*)d_out;

  char* p = (char*)d_ws;
  char* pend = p + ws_size;
  auto carve = [&](size_t bytes) -> void* {
    void* r = (void*)p;
    p += (bytes + 255) & ~(size_t)255;
    return r;
  };
  int*   cnt   = (int*)carve((size_t)N2 * 4);
  int*   off   = (int*)carve((size_t)(N2 + 1) * 4);
  float* dinv  = (float*)carve((size_t)N2 * 4);
  int*   csr   = (int*)carve((size_t)2 * E * 4);
  int*   bsum  = (int*)carve(256 * 4);
  float* stats = (float*)carve(512 * 4);  // sum[128] sumsq[128] scale[128] shift[128]
  unsigned short* Wp = (unsigned short*)carve((size_t)12 * 32768 * 2);  // 12 slots hi+lo
  float* tbuf = (float*)carve(ND * 4);    // relu intermediates (heads)

  float* hbuf = out + 2 * ND;  // fp32 aggregation output, p1 slot (dead until p1 write)
  _Float16 *tab0, *tab1;
  if ((size_t)(pend - p) >= 4 * ND + 512) {
    tab0 = (_Float16*)carve(2 * ND);
    tab1 = (_Float16*)carve(2 * ND);
  } else {
    tab0 = (_Float16*)(out + 3 * ND);  // p2 slot (dead until final write)
    tab1 = tab0 + ND;
  }

  const int TPB = 256;
  const int gridE = (E + TPB - 1) / TPB;
  const int nbScan = (N2 + 511) / 512;   // <=256 for N<=65536
  const int gridDual = (N + 63) / 64;
  const int gridHead = (N + 127) / 128;
  const int gridGath = (N + 15) / 16;
  float* bnsc = stats + 256;
  float* bnsh = stats + 384;

  // --- pack all 12 weight matrices (one launch) ---
  WPtrs P;
  P.w[0] = W0;              P.w[1] = W1;               // layer 0
  P.w[2] = W0 + (size_t)D * D;     P.w[3] = W1 + (size_t)D * D;
  P.w[4] = W0 + (size_t)2 * D * D; P.w[5] = W1 + (size_t)2 * D * D;
  P.w[6] = emb1_W; P.w[7] = emb2_W;
  P.w[8] = ph1_Wa; P.w[9] = ph1_Wb;
  P.w[10] = ph2_Wa; P.w[11] = ph2_Wb;
  pack_all_kernel<<<768, TPB, 0, stream>>>(P, Wp);

  // --- CSR build ---
  hipMemsetAsync(cnt, 0, (size_t)N2 * 4, stream);
  count_kernel<<<gridE, TPB, 0, stream>>>(ei0 + E, ei1 + E, cnt, E, N);
  scan_part_kernel<<<nbScan, TPB, 0, stream>>>(cnt, off, bsum, N2);
  scan_bsum_kernel<<<1, TPB, 0, stream>>>(bsum, nbScan, off + N2);
  scan_add_kernel<<<nbScan, TPB, 0, stream>>>(off, bsum, cnt, dinv, N2);
  fill_kernel<<<gridE, TPB, 0, stream>>>(ei0, ei1, off, cnt, csr, E, N);

  // --- GCN layers (BN of previous layer folded into mm A-load) ---
  for (int i = 0; i < 3; i++) {
    const unsigned short* wslot = Wp + (size_t)(2 * i) * 32768;
    if (i == 0) {
      mm_mfma<16, 4, 4, 0, 0><<<gridDual, TPB, 0, stream>>>(
          wslot, x, nullptr, nullptr, nullptr, dinv, tab0, tab1, nullptr, N, N);
    } else {
      mm_mfma<16, 4, 4, 0, 1><<<gridDual, TPB, 0, stream>>>(
          wslot, hbuf, bnsc, bnsh, nullptr, dinv, tab0, tab1, nullptr, N, N);
    }
    gather_kernel<<<gridGath, TPB, 0, stream>>>(tab0, tab1, dinv, off, csr,
                                                b0 + i * D, b1 + i * D, hbuf, N, N);
    hipMemsetAsync(stats, 0, 256 * 4, stream);
    stats_kernel<<<200, TPB, 0, stream>>>(hbuf, stats, stats + 128, N, (N + 199) / 200);
    bn_coef_kernel<<<1, 128, 0, stream>>>(stats, stats + 128, gamma + i * D, beta + i * D,
                                          bnsc, bnsh, N);
  }

  // --- heads (layer-2 BN folded into e1/e2 A-load; chain in exact fp32) ---
  // e1 = tanh(h@emb1W+b) -> out0
  mm_mfma<8, 8, 2, 2, 2><<<gridHead, TPB, 0, stream>>>(
      Wp + (size_t)6 * 32768, hbuf, bnsc, bnsh, emb1_b, nullptr, nullptr, nullptr, out, N, N);
  // e2 = l2norm(tanh(h@emb2W+b)) -> out1
  mm_mfma<8, 8, 2, 3, 2><<<gridHead, TPB, 0, stream>>>(
      Wp + (size_t)7 * 32768, hbuf, bnsc, bnsh, emb2_b, nullptr, nullptr, nullptr, out + ND, N, N);
  // t1 = relu(e1@ph1_Wa+ba) -> tbuf
  mm_mfma<8, 8, 2, 1, 0><<<gridHead, TPB, 0, stream>>>(
      Wp + (size_t)8 * 32768, out, nullptr, nullptr, ph1_ba, nullptr, nullptr, nullptr, tbuf, N, N);
  // p1 = l2norm(t1@ph1_Wb+bb) -> out2 (overwrites hbuf slot; hbuf dead after e2)
  mm_mfma<8, 8, 2, 4, 0><<<gridHead, TPB, 0, stream>>>(
      Wp + (size_t)9 * 32768, tbuf, nullptr, nullptr, ph1_bb, nullptr, nullptr, nullptr, out + 2 * ND, N, N);
  // t2 = relu(e2@ph2_Wa+ba) -> tbuf
  mm_mfma<8, 8, 2, 1, 0><<<gridHead, TPB, 0, stream>>>(
      Wp + (size_t)10 * 32768, out + ND, nullptr, nullptr, ph2_ba, nullptr, nullptr, nullptr, tbuf, N, N);
  // p2 = l2norm(t2@ph2_Wb+bb) -> out3 (overwrites tab slot if fallback; tabs dead)
  mm_mfma<8, 8, 2, 4, 0><<<gridHead, TPB, 0, stream>>>(
      Wp + (size_t)11 * 32768, tbuf, nullptr, nullptr, ph2_bb, nullptr, nullptr, nullptr, out + 3 * ND, N, N);
}

// Round 5
// 401.237 us; speedup vs baseline: 2.2284x; 1.3030x over previous
//
#include <hip/hip_runtime.h>
#include <cstdint>
#include <cstddef>

#define D 128

typedef __attribute__((ext_vector_type(8))) short bf16x8;
typedef __attribute__((ext_vector_type(4))) float f32x4;
typedef __attribute__((ext_vector_type(8))) _Float16 f16x8;

__device__ __forceinline__ unsigned short f2bf(float f) {
  unsigned int u = __float_as_uint(f);
  unsigned int r = u + 0x7FFFu + ((u >> 16) & 1u);
  return (unsigned short)(r >> 16);
}
__device__ __forceinline__ float bf2f(unsigned short h) {
  return __uint_as_float((unsigned int)h << 16);
}

// ---------------- weight packing (all 12 matrices, one launch) ----------------
// slot m: hi at Wp[m*32768 + r], lo at Wp[m*32768 + 16384 + r]
// r = ((jt*4+ks)*64+lane)*8 + b  ->  W[(ks*32+(lane>>4)*8+b)*128 + jt*16+(lane&15)]
struct WPtrs { const float* w[12]; };

__global__ __launch_bounds__(256) void pack_all_kernel(WPtrs P, unsigned short* __restrict__ Wp) {
  int tid = blockIdx.x * blockDim.x + threadIdx.x;  // 0..196607
  int m = tid >> 14;
  int r = tid & 16383;
  int b = r & 7, lane = (r >> 3) & 63, ks = (r >> 9) & 3, jt = r >> 11;
  int k = ks * 32 + ((lane >> 4) << 3) + b;
  int j = jt * 16 + (lane & 15);
  float w = P.w[m][k * 128 + j];
  unsigned short h = f2bf(w);
  Wp[m * 32768 + r] = h;
  Wp[m * 32768 + 16384 + r] = f2bf(w - bf2f(h));
}

// ---------------- CSR build (concatenated: type0=[0,N), type1=[N,2N)) ----------------
__global__ void count_kernel(const int* __restrict__ d0, const int* __restrict__ d1,
                             int* __restrict__ cnt, int E, int N) {
  int e = blockIdx.x * blockDim.x + threadIdx.x;
  if (e < E) {
    atomicAdd(&cnt[d0[e]], 1);
    atomicAdd(&cnt[N + d1[e]], 1);
  }
}

__global__ __launch_bounds__(256) void scan_part_kernel(const int* __restrict__ cnt,
                                                        int* __restrict__ off,
                                                        int* __restrict__ bsum, int n2) {
  __shared__ int sh[256];
  int t = threadIdx.x;
  int i0 = blockIdx.x * 512 + 2 * t;
  int a0 = (i0 < n2) ? cnt[i0] : 0;
  int a1 = (i0 + 1 < n2) ? cnt[i0 + 1] : 0;
  int s = a0 + a1;
  sh[t] = s;
  __syncthreads();
  for (int d = 1; d < 256; d <<= 1) {
    int v = (t >= d) ? sh[t - d] : 0;
    __syncthreads();
    sh[t] += v;
    __syncthreads();
  }
  int p = sh[t] - s;
  if (i0 < n2) off[i0] = p;
  if (i0 + 1 < n2) off[i0 + 1] = p + a0;
  if (t == 255) bsum[blockIdx.x] = sh[255];
}

__global__ __launch_bounds__(256) void scan_bsum_kernel(int* __restrict__ bsum, int nb,
                                                        int* __restrict__ off_total) {
  __shared__ int sh[256];
  int t = threadIdx.x;
  int s = (t < nb) ? bsum[t] : 0;
  sh[t] = s;
  __syncthreads();
  for (int d = 1; d < 256; d <<= 1) {
    int v = (t >= d) ? sh[t - d] : 0;
    __syncthreads();
    sh[t] += v;
    __syncthreads();
  }
  if (t < nb) bsum[t] = sh[t] - s;
  if (t == 255) *off_total = sh[255];
}

__global__ __launch_bounds__(256) void scan_add_kernel(int* __restrict__ off,
                                                       const int* __restrict__ bsum,
                                                       int* __restrict__ cnt,
                                                       float* __restrict__ dinv, int n2) {
  int add = bsum[blockIdx.x];
  int base = blockIdx.x * 512;
#pragma unroll
  for (int u = 0; u < 2; u++) {
    int i = base + threadIdx.x + u * 256;
    if (i < n2) {
      off[i] += add;
      dinv[i] = rsqrtf((float)cnt[i] + 1.0f);
      cnt[i] = 0;
    }
  }
}

__global__ void fill_kernel(const int* __restrict__ ei0, const int* __restrict__ ei1,
                            const int* __restrict__ off, int* __restrict__ cnt,
                            int* __restrict__ csr, int E, int N) {
  int e = blockIdx.x * blockDim.x + threadIdx.x;
  if (e < E) {
    int s = ei0[e], d = ei0[E + e];
    int p = atomicAdd(&cnt[d], 1);
    csr[off[d] + p] = s;
    s = ei1[e]; d = ei1[E + e];
    p = atomicAdd(&cnt[N + d], 1);
    csr[off[N + d] + p] = s;
  }
}

// ---------------- split helpers ----------------
__device__ __forceinline__ void split8(const float vv[8], bf16x8& hh, bf16x8& hl) {
#pragma unroll
  for (int c = 0; c < 8; c++) {
    unsigned short h = f2bf(vv[c]);
    hh[c] = (short)h;
    hl[c] = (short)f2bf(vv[c] - bf2f(h));
  }
}

// ---------------- dual GCN matmul (operand-swapped, split precision) ----------------
// tab{0,1}[i][j] = dinv_src * (sum_k W{0,1}[k][j] * BNrelu(A[i][k]))  (fp16)
template <int BN>
__global__ __launch_bounds__(256) void mm_dual(
    const unsigned short* __restrict__ Wp, const float* __restrict__ Af,
    const float* __restrict__ stats, const float* __restrict__ g0,
    const float* __restrict__ bt0, const float* __restrict__ dinv,
    _Float16* __restrict__ tab0, _Float16* __restrict__ tab1,
    int n, int N, float invn) {
  __shared__ float bnsc[128], bnsh[128];
  if (BN) {
    int t = threadIdx.x;
    if (t < 128) {
      float s = 0.f, q = 0.f;
#pragma unroll
      for (int r = 0; r < 8; r++) { s += stats[r * 128 + t]; q += stats[1024 + r * 128 + t]; }
      float mu = s * invn, var = q * invn - mu * mu;
      float sc = g0[t] * rsqrtf(var + 1e-5f);
      bnsc[t] = sc; bnsh[t] = bt0[t] - mu * sc;
    }
    __syncthreads();
  }
  constexpr int WJT = 4, WIT = 4;
  const int lane = threadIdx.x & 63;
  const int wid = threadIdx.x >> 6;
  const int wj = wid % 4, wi = wid / 4;   // JSPLIT=4 -> wi==0
  const int jtbase = wj * WJT;
  const int ibase = blockIdx.x * 64 + wi * WIT * 16;
  const int lrow = lane & 15, lgrp = lane >> 4;

  int node[WIT];
  bool valid[WIT];
#pragma unroll
  for (int it = 0; it < WIT; it++) {
    int i = ibase + it * 16 + lrow;
    valid[it] = (i < n);
    node[it] = valid[it] ? i : (n - 1);
  }

  f32x4 acc[WJT][WIT];
#pragma unroll
  for (int jt = 0; jt < WJT; jt++)
#pragma unroll
    for (int it = 0; it < WIT; it++) acc[jt][it] = (f32x4){0.f, 0.f, 0.f, 0.f};

#pragma unroll
  for (int ks = 0; ks < 4; ks++) {
    float sck[8], shk[8];
    if (BN) {
      int cb = ks * 32 + lgrp * 8;
#pragma unroll
      for (int c = 0; c < 8; c++) { sck[c] = bnsc[cb + c]; shk[c] = bnsh[cb + c]; }
    }
    bf16x8 awh[WJT], awl[WJT];
#pragma unroll
    for (int jt = 0; jt < WJT; jt++) {
      int jg = jtbase + jt;
      const unsigned short* base = Wp + ((jg >= 8) ? 32768 : 0);
      size_t fo = (size_t)(((jg & 7) * 4 + ks) * 64 + lane) * 8;
      awh[jt] = *(const bf16x8*)(base + fo);
      awl[jt] = *(const bf16x8*)(base + fo + 16384);
    }
#pragma unroll
    for (int it = 0; it < WIT; it++) {
      const float* src = Af + (size_t)node[it] * 128 + ks * 32 + lgrp * 8;
      float4 u0 = *(const float4*)src;
      float4 u1 = *(const float4*)(src + 4);
      float vv[8] = {u0.x, u0.y, u0.z, u0.w, u1.x, u1.y, u1.z, u1.w};
      if (BN) {
#pragma unroll
        for (int c = 0; c < 8; c++) vv[c] = fmaxf(vv[c] * sck[c] + shk[c], 0.f);
      }
      bf16x8 bhh, bhl;
      split8(vv, bhh, bhl);
#pragma unroll
      for (int jt = 0; jt < WJT; jt++) {
        acc[jt][it] = __builtin_amdgcn_mfma_f32_16x16x32_bf16(awh[jt], bhh, acc[jt][it], 0, 0, 0);
        acc[jt][it] = __builtin_amdgcn_mfma_f32_16x16x32_bf16(awl[jt], bhh, acc[jt][it], 0, 0, 0);
        acc[jt][it] = __builtin_amdgcn_mfma_f32_16x16x32_bf16(awh[jt], bhl, acc[jt][it], 0, 0, 0);
      }
    }
  }

#pragma unroll
  for (int it = 0; it < WIT; it++) {
    if (!valid[it]) continue;
    float d0v = dinv[node[it]];
    float d1v = dinv[N + node[it]];
#pragma unroll
    for (int jt = 0; jt < WJT; jt++) {
      int jg = jtbase + jt;
      float s = (jg < 8) ? d0v : d1v;
      _Float16 o[4];
#pragma unroll
      for (int c = 0; c < 4; c++) o[c] = (_Float16)(acc[jt][it][c] * s);
      _Float16* base = (jg < 8)
          ? (tab0 + (size_t)node[it] * 128 + jg * 16)
          : (tab1 + (size_t)node[it] * 128 + (jg - 8) * 16);
      *(uint2*)(base + lgrp * 4) = *(uint2*)o;
    }
  }
}

// ---------------- gather + fused BN stats ----------------
__global__ __launch_bounds__(256) void gather_kernel(
    const _Float16* __restrict__ tab0, const _Float16* __restrict__ tab1,
    const float* __restrict__ dinv, const int* __restrict__ off,
    const int* __restrict__ csr,
    const float* __restrict__ b0, const float* __restrict__ b1,
    float* __restrict__ outh, float* __restrict__ stats, int n, int N) {
  __shared__ float reds[4][128];
  __shared__ float redq[4][128];
  int t = threadIdx.x;
  int g = t >> 4, l = t & 15;
  int node = blockIdx.x * 16 + g;
  bool valid = node < n;
  int nd = valid ? node : 0;
  const f16x8* t0 = (const f16x8*)tab0;
  const f16x8* t1 = (const f16x8*)tab1;
  float s0[8] = {0,0,0,0,0,0,0,0}, s1[8] = {0,0,0,0,0,0,0,0};
  if (valid) {
    f16x8 v = t0[(size_t)nd * 16 + l];
#pragma unroll
    for (int c = 0; c < 8; c++) s0[c] = (float)v[c];
    v = t1[(size_t)nd * 16 + l];
#pragma unroll
    for (int c = 0; c < 8; c++) s1[c] = (float)v[c];
  }
  int a = valid ? off[nd] : 0, b = valid ? off[nd + 1] : 0;
  int j = a;
  for (; j + 1 < b; j += 2) {
    int sa = csr[j], sb = csr[j + 1];
    f16x8 va = t0[(size_t)sa * 16 + l];
    f16x8 vb = t0[(size_t)sb * 16 + l];
#pragma unroll
    for (int c = 0; c < 8; c++) s0[c] += (float)va[c] + (float)vb[c];
  }
  if (j < b) {
    f16x8 va = t0[(size_t)csr[j] * 16 + l];
#pragma unroll
    for (int c = 0; c < 8; c++) s0[c] += (float)va[c];
  }
  a = valid ? off[N + nd] : 0; b = valid ? off[N + nd + 1] : 0;
  j = a;
  for (; j + 1 < b; j += 2) {
    int sa = csr[j], sb = csr[j + 1];
    f16x8 va = t1[(size_t)sa * 16 + l];
    f16x8 vb = t1[(size_t)sb * 16 + l];
#pragma unroll
    for (int c = 0; c < 8; c++) s1[c] += (float)va[c] + (float)vb[c];
  }
  if (j < b) {
    f16x8 va = t1[(size_t)csr[j] * 16 + l];
#pragma unroll
    for (int c = 0; c < 8; c++) s1[c] += (float)va[c];
  }
  float o[8] = {0,0,0,0,0,0,0,0};
  if (valid) {
    float d0 = dinv[nd], d1 = dinv[N + nd];
    const float4* B0 = (const float4*)(b0 + l * 8);
    const float4* B1 = (const float4*)(b1 + l * 8);
    float4 ba0 = B0[0], ba1 = B0[1], bb0 = B1[0], bb1 = B1[1];
    float bs[8] = {ba0.x + bb0.x, ba0.y + bb0.y, ba0.z + bb0.z, ba0.w + bb0.w,
                   ba1.x + bb1.x, ba1.y + bb1.y, ba1.z + bb1.z, ba1.w + bb1.w};
#pragma unroll
    for (int c = 0; c < 8; c++) o[c] = d0 * s0[c] + d1 * s1[c] + bs[c];
    float* dst = outh + (size_t)nd * 128 + l * 8;
    *(float4*)dst = make_float4(o[0], o[1], o[2], o[3]);
    *(float4*)(dst + 4) = make_float4(o[4], o[5], o[6], o[7]);
  }
  // fused BN statistics
  float sv[8], q[8];
#pragma unroll
  for (int c = 0; c < 8; c++) { sv[c] = o[c]; q[c] = o[c] * o[c]; }
#pragma unroll
  for (int c = 0; c < 8; c++) {
    sv[c] += __shfl_xor(sv[c], 16); sv[c] += __shfl_xor(sv[c], 32);
    q[c] += __shfl_xor(q[c], 16);  q[c] += __shfl_xor(q[c], 32);
  }
  int lane = t & 63, wid = t >> 6;
  if (lane < 16) {
#pragma unroll
    for (int c = 0; c < 8; c++) { reds[wid][lane * 8 + c] = sv[c]; redq[wid][lane * 8 + c] = q[c]; }
  }
  __syncthreads();
  if (t < 128) {
    float ts = reds[0][t] + reds[1][t] + reds[2][t] + reds[3][t];
    float tq = redq[0][t] + redq[1][t] + redq[2][t] + redq[3][t];
    int cp = blockIdx.x & 7;
    atomicAdd(&stats[cp * 128 + t], ts);
    atomicAdd(&stats[1024 + cp * 128 + t], tq);
  }
}

// ---------------- fused head chain: e1,e2,t1,p1,t2,p2 in one kernel ----------------
// 2 waves/block, each wave owns 16 nodes x all 128 features; LDS tile bounce.
__device__ __forceinline__ void head_acc_init(const float* bias, int lgrp, f32x4 acc[8]) {
#pragma unroll
  for (int jt = 0; jt < 8; jt++) {
    float4 b4 = *(const float4*)(bias + jt * 16 + lgrp * 4);
    acc[jt] = (f32x4){b4.x, b4.y, b4.z, b4.w};
  }
}
__device__ __forceinline__ void head_mm_frag(const unsigned short* slot, int ks, int lane,
                                             const float vv[8], f32x4 acc[8]) {
  bf16x8 bhh, bhl;
  split8(vv, bhh, bhl);
#pragma unroll
  for (int jt = 0; jt < 8; jt++) {
    size_t fo = (size_t)((jt * 4 + ks) * 64 + lane) * 8;
    bf16x8 awh = *(const bf16x8*)(slot + fo);
    bf16x8 awl = *(const bf16x8*)(slot + fo + 16384);
    acc[jt] = __builtin_amdgcn_mfma_f32_16x16x32_bf16(awh, bhh, acc[jt], 0, 0, 0);
    acc[jt] = __builtin_amdgcn_mfma_f32_16x16x32_bf16(awl, bhh, acc[jt], 0, 0, 0);
    acc[jt] = __builtin_amdgcn_mfma_f32_16x16x32_bf16(awh, bhl, acc[jt], 0, 0, 0);
  }
}
__device__ __forceinline__ void head_l2norm(f32x4 acc[8]) {
  float rs = 0.f;
#pragma unroll
  for (int jt = 0; jt < 8; jt++)
#pragma unroll
    for (int c = 0; c < 4; c++) rs += acc[jt][c] * acc[jt][c];
  rs += __shfl_xor(rs, 16);
  rs += __shfl_xor(rs, 32);
  float scl = 1.f / fmaxf(sqrtf(rs), 1e-12f);
#pragma unroll
  for (int jt = 0; jt < 8; jt++)
#pragma unroll
    for (int c = 0; c < 4; c++) acc[jt][c] *= scl;
}
__device__ __forceinline__ void head_st_global(float* o, int nidx, bool valid, int lgrp,
                                               const f32x4 acc[8]) {
  if (!valid) return;
#pragma unroll
  for (int jt = 0; jt < 8; jt++)
    *(float4*)(o + (size_t)nidx * 128 + jt * 16 + lgrp * 4) =
        make_float4(acc[jt][0], acc[jt][1], acc[jt][2], acc[jt][3]);
}
__device__ __forceinline__ void head_st_lds(float* tile, int lrow, int lgrp, const f32x4 acc[8]) {
#pragma unroll
  for (int jt = 0; jt < 8; jt++)
    *(float4*)(tile + lrow * 132 + jt * 16 + lgrp * 4) =
        make_float4(acc[jt][0], acc[jt][1], acc[jt][2], acc[jt][3]);
}

__global__ __launch_bounds__(128) void heads_kernel(
    const unsigned short* __restrict__ Wp,   // slots 6..11
    const float* __restrict__ h, const float* __restrict__ stats,
    const float* __restrict__ g2, const float* __restrict__ bt2,
    const float* __restrict__ emb1_b, const float* __restrict__ emb2_b,
    const float* __restrict__ ph1_ba, const float* __restrict__ ph1_bb,
    const float* __restrict__ ph2_ba, const float* __restrict__ ph2_bb,
    float* __restrict__ out, int n, float invn) {
  __shared__ float bnsc[128], bnsh[128];
  __shared__ float tileA[2][16 * 132];
  __shared__ float tileB[2][16 * 132];
  int t = threadIdx.x;
  {
    float s = 0.f, q = 0.f;
#pragma unroll
    for (int r = 0; r < 8; r++) { s += stats[r * 128 + t]; q += stats[1024 + r * 128 + t]; }
    float mu = s * invn, var = q * invn - mu * mu;
    float sc = g2[t] * rsqrtf(var + 1e-5f);
    bnsc[t] = sc; bnsh[t] = bt2[t] - mu * sc;
  }
  __syncthreads();
  const int lane = t & 63, wid = t >> 6;
  const int lrow = lane & 15, lgrp = lane >> 4;
  int node = blockIdx.x * 32 + wid * 16 + lrow;
  bool valid = node < n;
  int nidx = valid ? node : (n - 1);
  float* A = &tileA[wid][0];
  float* B = &tileB[wid][0];
  const size_t ND = (size_t)n * 128;
  f32x4 acc[8];

  // stage e1 = tanh(h@W6 + emb1_b) -> out0, tileA
  head_acc_init(emb1_b, lgrp, acc);
#pragma unroll
  for (int ks = 0; ks < 4; ks++) {
    const float* src = h + (size_t)nidx * 128 + ks * 32 + lgrp * 8;
    float4 u0 = *(const float4*)src;
    float4 u1 = *(const float4*)(src + 4);
    float vv[8] = {u0.x, u0.y, u0.z, u0.w, u1.x, u1.y, u1.z, u1.w};
    int cb = ks * 32 + lgrp * 8;
#pragma unroll
    for (int c = 0; c < 8; c++) vv[c] = vv[c] * bnsc[cb + c] + bnsh[cb + c];
    head_mm_frag(Wp + (size_t)6 * 32768, ks, lane, vv, acc);
  }
#pragma unroll
  for (int jt = 0; jt < 8; jt++)
#pragma unroll
    for (int c = 0; c < 4; c++) acc[jt][c] = tanhf(acc[jt][c]);
  head_st_global(out, nidx, valid, lgrp, acc);
  head_st_lds(A, lrow, lgrp, acc);

  // stage e2 = l2norm(tanh(h@W7 + emb2_b)) -> out1, tileB
  head_acc_init(emb2_b, lgrp, acc);
#pragma unroll
  for (int ks = 0; ks < 4; ks++) {
    const float* src = h + (size_t)nidx * 128 + ks * 32 + lgrp * 8;
    float4 u0 = *(const float4*)src;
    float4 u1 = *(const float4*)(src + 4);
    float vv[8] = {u0.x, u0.y, u0.z, u0.w, u1.x, u1.y, u1.z, u1.w};
    int cb = ks * 32 + lgrp * 8;
#pragma unroll
    for (int c = 0; c < 8; c++) vv[c] = vv[c] * bnsc[cb + c] + bnsh[cb + c];
    head_mm_frag(Wp + (size_t)7 * 32768, ks, lane, vv, acc);
  }
#pragma unroll
  for (int jt = 0; jt < 8; jt++)
#pragma unroll
    for (int c = 0; c < 4; c++) acc[jt][c] = tanhf(acc[jt][c]);
  head_l2norm(acc);
  head_st_global(out + ND, nidx, valid, lgrp, acc);
  head_st_lds(B, lrow, lgrp, acc);

  // stage t1 = relu(e1@W8 + ph1_ba) -> tileA
  head_acc_init(ph1_ba, lgrp, acc);
#pragma unroll
  for (int ks = 0; ks < 4; ks++) {
    const float* src = A + lrow * 132 + ks * 32 + lgrp * 8;
    float4 u0 = *(const float4*)src;
    float4 u1 = *(const float4*)(src + 4);
    float vv[8] = {u0.x, u0.y, u0.z, u0.w, u1.x, u1.y, u1.z, u1.w};
    head_mm_frag(Wp + (size_t)8 * 32768, ks, lane, vv, acc);
  }
#pragma unroll
  for (int jt = 0; jt < 8; jt++)
#pragma unroll
    for (int c = 0; c < 4; c++) acc[jt][c] = fmaxf(acc[jt][c], 0.f);
  head_st_lds(A, lrow, lgrp, acc);

  // stage p1 = l2norm(t1@W9 + ph1_bb) -> out2
  head_acc_init(ph1_bb, lgrp, acc);
#pragma unroll
  for (int ks = 0; ks < 4; ks++) {
    const float* src = A + lrow * 132 + ks * 32 + lgrp * 8;
    float4 u0 = *(const float4*)src;
    float4 u1 = *(const float4*)(src + 4);
    float vv[8] = {u0.x, u0.y, u0.z, u0.w, u1.x, u1.y, u1.z, u1.w};
    head_mm_frag(Wp + (size_t)9 * 32768, ks, lane, vv, acc);
  }
  head_l2norm(acc);
  head_st_global(out + 2 * ND, nidx, valid, lgrp, acc);

  // stage t2 = relu(e2@W10 + ph2_ba) -> tileB
  head_acc_init(ph2_ba, lgrp, acc);
#pragma unroll
  for (int ks = 0; ks < 4; ks++) {
    const float* src = B + lrow * 132 + ks * 32 + lgrp * 8;
    float4 u0 = *(const float4*)src;
    float4 u1 = *(const float4*)(src + 4);
    float vv[8] = {u0.x, u0.y, u0.z, u0.w, u1.x, u1.y, u1.z, u1.w};
    head_mm_frag(Wp + (size_t)10 * 32768, ks, lane, vv, acc);
  }
#pragma unroll
  for (int jt = 0; jt < 8; jt++)
#pragma unroll
    for (int c = 0; c < 4; c++) acc[jt][c] = fmaxf(acc[jt][c], 0.f);
  head_st_lds(B, lrow, lgrp, acc);

  // stage p2 = l2norm(t2@W11 + ph2_bb) -> out3
  head_acc_init(ph2_bb, lgrp, acc);
#pragma unroll
  for (int ks = 0; ks < 4; ks++) {
    const float* src = B + lrow * 132 + ks * 32 + lgrp * 8;
    float4 u0 = *(const float4*)src;
    float4 u1 = *(const float4*)(src + 4);
    float vv[8] = {u0.x, u0.y, u0.z, u0.w, u1.x, u1.y, u1.z, u1.w};
    head_mm_frag(Wp + (size_t)11 * 32768, ks, lane, vv, acc);
  }
  head_l2norm(acc);
  head_st_global(out + 3 * ND, nidx, valid, lgrp, acc);
}

// ---------------- launch ----------------
extern "C" void kernel_launch(void* const* d_in, const int* in_sizes, int n_in,
                              void* d_out, int out_size, void* d_ws, size_t ws_size,
                              hipStream_t stream) {
  const float* x      = (const float*)d_in[0];
  const int*   ei0    = (const int*)d_in[1];
  const int*   ei1    = (const int*)d_in[2];
  const float* W0     = (const float*)d_in[3];
  const float* b0     = (const float*)d_in[4];
  const float* W1     = (const float*)d_in[5];
  const float* b1     = (const float*)d_in[6];
  const float* gamma  = (const float*)d_in[7];
  const float* beta   = (const float*)d_in[8];
  const float* emb1_W = (const float*)d_in[9];
  const float* emb1_b = (const float*)d_in[10];
  const float* emb2_W = (const float*)d_in[11];
  const float* emb2_b = (const float*)d_in[12];
  const float* ph1_Wa = (const float*)d_in[13];
  const float* ph1_ba = (const float*)d_in[14];
  const float* ph1_Wb = (const float*)d_in[15];
  const float* ph1_bb = (const float*)d_in[16];
  const float* ph2_Wa = (const float*)d_in[17];
  const float* ph2_ba = (const float*)d_in[18];
  const float* ph2_Wb = (const float*)d_in[19];
  const float* ph2_bb = (const float*)d_in[20];

  const int N = in_sizes[0] / D;
  const int E = in_sizes[1] / 2;
  const int N2 = 2 * N;
  const size_t ND = (size_t)N * D;
  const float invn = 1.0f / (float)N;
  float* out = (float*)d_out;

  char* p = (char*)d_ws;
  char* pend = p + ws_size;
  auto carve = [&](size_t bytes) -> void* {
    void* r = (void*)p;
    p += (bytes + 255) & ~(size_t)255;
    return r;
  };
  int*   cnt   = (int*)carve((size_t)N2 * 4);
  int*   off   = (int*)carve((size_t)(N2 + 1) * 4);
  float* dinv  = (float*)carve((size_t)N2 * 4);
  int*   csr   = (int*)carve((size_t)2 * E * 4);
  int*   bsum  = (int*)carve(256 * 4);
  float* stats = (float*)carve(2048 * 4);   // [2][8][128] replicated sums / sumsq
  unsigned short* Wp = (unsigned short*)carve((size_t)12 * 32768 * 2);

  float* hbuf;
  _Float16 *tab0, *tab1;
  size_t avail = (size_t)(pend - p);
  if (avail >= 8 * ND + 1024) {
    hbuf = (float*)carve(4 * ND);
    tab0 = (_Float16*)carve(2 * ND);
    tab1 = (_Float16*)carve(2 * ND);
  } else if (avail >= 4 * ND + 512) {
    hbuf = out + 2 * ND;                    // p1 slot; safe (see heads ordering)
    tab0 = (_Float16*)carve(2 * ND);
    tab1 = (_Float16*)carve(2 * ND);
  } else {
    hbuf = out + 2 * ND;
    tab0 = (_Float16*)(out + 3 * ND);       // p2 slot; tabs dead before p2 write
    tab1 = tab0 + ND;
  }

  const int TPB = 256;
  const int gridE = (E + TPB - 1) / TPB;
  const int nbScan = (N2 + 511) / 512;
  const int gridDual = (N + 63) / 64;
  const int gridGath = (N + 15) / 16;
  const int gridHead = (N + 31) / 32;

  // pack all 12 weight matrices
  WPtrs P;
  P.w[0] = W0;                     P.w[1] = W1;
  P.w[2] = W0 + (size_t)D * D;     P.w[3] = W1 + (size_t)D * D;
  P.w[4] = W0 + (size_t)2 * D * D; P.w[5] = W1 + (size_t)2 * D * D;
  P.w[6] = emb1_W; P.w[7] = emb2_W;
  P.w[8] = ph1_Wa; P.w[9] = ph1_Wb;
  P.w[10] = ph2_Wa; P.w[11] = ph2_Wb;
  pack_all_kernel<<<768, TPB, 0, stream>>>(P, Wp);

  // CSR build
  hipMemsetAsync(cnt, 0, (size_t)N2 * 4, stream);
  count_kernel<<<gridE, TPB, 0, stream>>>(ei0 + E, ei1 + E, cnt, E, N);
  scan_part_kernel<<<nbScan, TPB, 0, stream>>>(cnt, off, bsum, N2);
  scan_bsum_kernel<<<1, TPB, 0, stream>>>(bsum, nbScan, off + N2);
  scan_add_kernel<<<nbScan, TPB, 0, stream>>>(off, bsum, cnt, dinv, N2);
  fill_kernel<<<gridE, TPB, 0, stream>>>(ei0, ei1, off, cnt, csr, E, N);

  // GCN layers
  for (int i = 0; i < 3; i++) {
    const unsigned short* wslot = Wp + (size_t)(2 * i) * 32768;
    if (i == 0) {
      mm_dual<0><<<gridDual, TPB, 0, stream>>>(wslot, x, nullptr, nullptr, nullptr,
                                               dinv, tab0, tab1, N, N, invn);
    } else {
      mm_dual<1><<<gridDual, TPB, 0, stream>>>(wslot, hbuf, stats, gamma + (i - 1) * D,
                                               beta + (i - 1) * D, dinv, tab0, tab1, N, N, invn);
    }
    hipMemsetAsync(stats, 0, 2048 * 4, stream);
    gather_kernel<<<gridGath, TPB, 0, stream>>>(tab0, tab1, dinv, off, csr,
                                                b0 + i * D, b1 + i * D, hbuf, stats, N, N);
  }

  // fused heads (layer-2 BN folded into the h-loads)
  heads_kernel<<<gridHead, 128, 0, stream>>>(
      Wp, hbuf, stats, gamma + 2 * D, beta + 2 * D,
      emb1_b, emb2_b, ph1_ba, ph1_bb, ph2_ba, ph2_bb, out, N, invn);
}